// Round 5
// baseline (108.987 us; speedup 1.0000x reference)
//
#include <hip/hip_runtime.h>
#include <stdint.h>

#define BB   4
#define NQ   8192
#define NS   4096
#define FDIM 256
#define KNN  8
#define G    16             // lanes per sensor-stripe group
#define QL   4              // queries register-tiled per group
#define NT   256            // threads per block
#define GRP  (NT / G)       // 16 groups per block
#define QPB  (GRP * QL)     // 64 queries per block
#define SCAN (NS / G)       // 256 sensors per lane
#define CAP  16             // collection capacity per query (ties spill)

typedef unsigned long long u64;

// Selection key x' = s^2 - 2 q.s (= d^2 - q^2, monotone in d^2).
// Fixed rounding ops -> bit-identical between pass A and pass C.
#define KEYX(m, qq) __fmaf_rn(qx[qq], (m).x, \
                    __fmaf_rn(qy[qq], (m).y, \
                    __fmaf_rn(qz[qq], (m).z, (m).w)))

__device__ __forceinline__ float med3(float a, float b, float c) {
    return __builtin_amdgcn_fmed3f(a, b, c);
}

__global__ __launch_bounds__(NT, 2) void idw_kernel(
    const float* __restrict__ qc,   // (B*NQ, 3)
    const float* __restrict__ sc,   // (NS, 3)
    const float* __restrict__ sf,   // (B, NS, FDIM)
    float* __restrict__ out)        // (B*NQ, FDIM)
{
    __shared__ float4 s_m[NS];             // 64 KB: (-2x, -2y, -2z, |s|^2)
    __shared__ u64    s_items[QPB * CAP];  // 8 KB
    __shared__ int    s_cnt[QPB];
    __shared__ int    s_idx[QPB * KNN];
    __shared__ float  s_w[QPB * KNN];

    const int tid = threadIdx.x;

    // XCD-aware swizzle over 512 blocks: batch b -> XCD pair {2b,2b+1}
    // (round-robin dispatch assumption; bijective; locality-only).
    const int p   = blockIdx.x;
    const int b   = (p >> 1) & 3;
    const int sub = ((p >> 3) << 1) | (p & 1);   // 0..127
    const int q0  = b * NQ + sub * QPB;

    // ---- stage (-2x,-2y,-2z,s^2); zero counters ----
    for (int s = tid; s < NS; s += NT) {
        const float sx = sc[3*s+0], sy = sc[3*s+1], sz = sc[3*s+2];
        const float s2 = __fmaf_rn(sx, sx, __fmaf_rn(sy, sy, __fmul_rn(sz, sz)));
        s_m[s] = make_float4(-2.0f*sx, -2.0f*sy, -2.0f*sz, s2);
    }
    if (tid < QPB) s_cnt[tid] = 0;
    __syncthreads();

    const int g = tid >> 4;        // group in block: 0..15
    const int l = tid & 15;        // lane within group: 0..15

    // 4 queries per group, coords broadcast into registers
    float qx[QL], qy[QL], qz[QL], q2[QL];
    #pragma unroll
    for (int qq = 0; qq < QL; ++qq) {
        const float* qp = qc + (size_t)(q0 + g * QL + qq) * 3;
        qx[qq] = qp[0]; qy[qq] = qp[1]; qz[qq] = qp[2];
        q2[qq] = __fmaf_rn(qx[qq], qx[qq],
                 __fmaf_rn(qy[qq], qy[qq], __fmul_rn(qz[qq], qz[qq])));
    }

    // ---- pass A: per-lane sorted top-8 of x' for 4 queries, one LDS read ----
    float kd[QL][KNN];
    #pragma unroll
    for (int qq = 0; qq < QL; ++qq)
        #pragma unroll
        for (int j = 0; j < KNN; ++j) kd[qq][j] = 3.4e38f;

    #pragma unroll 2
    for (int t = 0; t < SCAN; ++t) {
        const float4 m = s_m[t * G + l];
        #pragma unroll
        for (int qq = 0; qq < QL; ++qq) {
            const float x = KEYX(m, qq);
            const float nk0 = fminf(kd[qq][0], x);
            #pragma unroll
            for (int j = KNN - 1; j >= 1; --j)
                kd[qq][j] = med3(kd[qq][j-1], kd[qq][j], x);
            kd[qq][0] = nk0;
        }
    }

    // ---- merge per query: 8-round pop-tournament over 16 lanes ----
    // Cross-lane exact ties over-pop -> thr only RAISED; spill caught below.
    float thr[QL];
    #pragma unroll
    for (int qq = 0; qq < QL; ++qq) {
        float th = 3.4e38f;
        #pragma unroll
        for (int r = 0; r < KNN; ++r) {
            float m = kd[qq][0];
            m = fminf(m, __shfl_xor(m, 1, 64));
            m = fminf(m, __shfl_xor(m, 2, 64));
            m = fminf(m, __shfl_xor(m, 4, 64));
            m = fminf(m, __shfl_xor(m, 8, 64));
            const bool pop = (kd[qq][0] == m);
            #pragma unroll
            for (int j = 0; j < KNN - 1; ++j) kd[qq][j] = pop ? kd[qq][j+1] : kd[qq][j];
            kd[qq][KNN-1] = pop ? 3.4e38f : kd[qq][KNN-1];
            th = m;
        }
        thr[qq] = th;
    }

    // ---- pass C: membership re-scan; collect (d^2, idx) of hits ----
    #pragma unroll 2
    for (int t = 0; t < SCAN; ++t) {
        const int s = t * G + l;
        const float4 m = s_m[s];
        #pragma unroll
        for (int qq = 0; qq < QL; ++qq) {
            const float x = KEYX(m, qq);
            if (x <= thr[qq]) {
                const float dc = fmaxf(__fadd_rn(x, q2[qq]), 0.0f);  // d^2
                const u64 key = ((u64)__float_as_uint(dc) << 32) | (unsigned)s;
                const int qid = g * QL + qq;
                const int pos = atomicAdd(&s_cnt[qid], 1);
                if (pos < CAP) s_items[qid * CAP + pos] = key;
            }
        }
    }
    __syncthreads();

    // ---- rare tie fix (lanes 0..3 of each group, one query each) ----
    if (l < QL) {
        const int qid = g * QL + l;
        int cnt = s_cnt[qid];
        if (cnt > KNN) {
            cnt = cnt < CAP ? cnt : CAP;
            u64 best[KNN];
            #pragma unroll
            for (int j = 0; j < KNN; ++j) best[j] = ~0ull;
            for (int i = 0; i < cnt; ++i) {
                const u64 key = s_items[qid * CAP + i];
                bool f[KNN];
                #pragma unroll
                for (int j = 0; j < KNN; ++j) f[j] = key < best[j];
                #pragma unroll
                for (int j = KNN - 1; j >= 1; --j)
                    best[j] = f[j-1] ? best[j-1] : (f[j] ? key : best[j]);
                best[0] = f[0] ? key : best[0];
            }
            #pragma unroll
            for (int j = 0; j < KNN; ++j) s_items[qid * CAP + j] = best[j];
        }
    }
    __syncthreads();

    // ---- weights: 16 lanes cover 2 queries x 8 slots per half ----
    #pragma unroll
    for (int half = 0; half < 2; ++half) {
        const int qq  = half * 2 + (l >> 3);   // 0..3
        const int k   = l & 7;
        const int qid = g * QL + qq;
        const u64 key = s_items[qid * CAP + k];
        const float d2v = __uint_as_float((unsigned)(key >> 32));
        const int   idx = (int)(unsigned)(key & 0xFFFFFFFFu);
        const float w   = 1.0f / (sqrtf(d2v) + 1e-8f);
        float ws = w;
        ws += __shfl_xor(ws, 1, 64);
        ws += __shfl_xor(ws, 2, 64);
        ws += __shfl_xor(ws, 4, 64);
        s_idx[qid * KNN + k] = idx;
        s_w  [qid * KNN + k] = w / ws;
    }
    __syncthreads();

    // ---- phase B: one wave per query, 64 lanes x float4 = 256 features ----
    const int wave = tid >> 6;       // 0..3
    const int lane = tid & 63;
    const float* fb = sf + (size_t)b * NS * FDIM;
    #pragma unroll 1
    for (int j = 0; j < QPB / 4; ++j) {          // 16 queries per wave
        const int ql = wave * (QPB / 4) + j;
        float4 acc = {0.f, 0.f, 0.f, 0.f};
        #pragma unroll
        for (int kk = 0; kk < KNN; ++kk) {
            const int   sid = s_idx[ql * KNN + kk];   // LDS broadcast
            const float wk  = s_w  [ql * KNN + kk];
            const float4 v = ((const float4*)(fb + (size_t)sid * FDIM))[lane];
            acc.x += wk * v.x; acc.y += wk * v.y;
            acc.z += wk * v.z; acc.w += wk * v.w;
        }
        ((float4*)(out + (size_t)(q0 + ql) * FDIM))[lane] = acc;
    }
}

extern "C" void kernel_launch(void* const* d_in, const int* in_sizes, int n_in,
                              void* d_out, int out_size, void* d_ws, size_t ws_size,
                              hipStream_t stream) {
    const float* qc = (const float*)d_in[0];   // query_coords  (4,8192,3)
    const float* sc = (const float*)d_in[1];   // sensor_coords (4096,3)
    const float* sf = (const float*)d_in[2];   // sensor_features (4,4096,256)
    float* out = (float*)d_out;                // (4,8192,256)

    dim3 grid((BB * NQ) / QPB);                // 512 blocks
    dim3 block(NT);
    idw_kernel<<<grid, block, 0, stream>>>(qc, sc, sf, out);
}

// Round 6
// 91.148 us; speedup vs baseline: 1.1957x; 1.1957x over previous
//
#include <hip/hip_runtime.h>
#include <stdint.h>

#define BB   4
#define NQ   8192
#define NS   4096
#define FDIM 256
#define KNN  8
#define G    16             // lanes per sensor-stripe group
#define QL   2              // queries register-tiled per group
#define NT   512            // threads per block
#define GRP  (NT / G)       // 32 groups per block
#define QPB  (GRP * QL)     // 64 queries per block
#define SCAN (NS / G)       // 256 sensors per lane
#define CAP  16             // collection capacity per query (ties spill)

typedef unsigned long long u64;

// Selection key x' = s^2 - 2 q.s (= d^2 - q^2, monotone in d^2).
// Fixed rounding ops -> bit-identical between pass A and pass C.
#define KEYX(m, qq) __fmaf_rn(qx[qq], (m).x, \
                    __fmaf_rn(qy[qq], (m).y, \
                    __fmaf_rn(qz[qq], (m).z, (m).w)))

__device__ __forceinline__ float med3(float a, float b, float c) {
    return __builtin_amdgcn_fmed3f(a, b, c);
}

__global__ __launch_bounds__(NT, 4) void idw_kernel(
    const float* __restrict__ qc,   // (B*NQ, 3)
    const float* __restrict__ sc,   // (NS, 3)
    const float* __restrict__ sf,   // (B, NS, FDIM)
    float* __restrict__ out)        // (B*NQ, FDIM)
{
    __shared__ float4 s_m[NS];             // 64 KB: (-2x, -2y, -2z, |s|^2)
    __shared__ u64    s_items[QPB * CAP];  // 8 KB
    __shared__ int    s_cnt[QPB];
    __shared__ int    s_idx[QPB * KNN];
    __shared__ float  s_w[QPB * KNN];

    const int tid = threadIdx.x;

    // XCD-aware swizzle over 512 blocks: batch b -> XCD pair {2b,2b+1}
    // (round-robin dispatch assumption; bijective; locality-only).
    const int p   = blockIdx.x;
    const int b   = (p >> 1) & 3;
    const int sub = ((p >> 3) << 1) | (p & 1);   // 0..127
    const int q0  = b * NQ + sub * QPB;

    // ---- stage (-2x,-2y,-2z,s^2); zero counters ----
    for (int s = tid; s < NS; s += NT) {
        const float sx = sc[3*s+0], sy = sc[3*s+1], sz = sc[3*s+2];
        const float s2 = __fmaf_rn(sx, sx, __fmaf_rn(sy, sy, __fmul_rn(sz, sz)));
        s_m[s] = make_float4(-2.0f*sx, -2.0f*sy, -2.0f*sz, s2);
    }
    if (tid < QPB) s_cnt[tid] = 0;
    __syncthreads();

    const int g = tid >> 4;        // group in block: 0..31
    const int l = tid & 15;        // lane within group: 0..15

    // QL queries per group, coords broadcast into registers
    float qx[QL], qy[QL], qz[QL], q2[QL];
    #pragma unroll
    for (int qq = 0; qq < QL; ++qq) {
        const float* qp = qc + (size_t)(q0 + g * QL + qq) * 3;
        qx[qq] = qp[0]; qy[qq] = qp[1]; qz[qq] = qp[2];
        q2[qq] = __fmaf_rn(qx[qq], qx[qq],
                 __fmaf_rn(qy[qq], qy[qq], __fmul_rn(qz[qq], qz[qq])));
    }

    // ---- pass A: per-lane sorted top-8 of x' for QL queries, one LDS read ----
    float kd[QL][KNN];
    #pragma unroll
    for (int qq = 0; qq < QL; ++qq)
        #pragma unroll
        for (int j = 0; j < KNN; ++j) kd[qq][j] = 3.4e38f;

    #pragma unroll 2
    for (int t = 0; t < SCAN; ++t) {
        const float4 m = s_m[t * G + l];   // 16 distinct float4 per wave (4-way bcast)
        #pragma unroll
        for (int qq = 0; qq < QL; ++qq) {
            const float x = KEYX(m, qq);
            const float nk0 = fminf(kd[qq][0], x);
            #pragma unroll
            for (int j = KNN - 1; j >= 1; --j)
                kd[qq][j] = med3(kd[qq][j-1], kd[qq][j], x);
            kd[qq][0] = nk0;
        }
    }

    // ---- merge per query: 8-round pop-tournament over 16 lanes ----
    // Cross-lane exact ties over-pop -> thr only RAISED; spill caught below.
    float thr[QL];
    #pragma unroll
    for (int qq = 0; qq < QL; ++qq) {
        float th = 3.4e38f;
        #pragma unroll
        for (int r = 0; r < KNN; ++r) {
            float m = kd[qq][0];
            m = fminf(m, __shfl_xor(m, 1, 64));
            m = fminf(m, __shfl_xor(m, 2, 64));
            m = fminf(m, __shfl_xor(m, 4, 64));
            m = fminf(m, __shfl_xor(m, 8, 64));
            const bool pop = (kd[qq][0] == m);
            #pragma unroll
            for (int j = 0; j < KNN - 1; ++j) kd[qq][j] = pop ? kd[qq][j+1] : kd[qq][j];
            kd[qq][KNN-1] = pop ? 3.4e38f : kd[qq][KNN-1];
            th = m;
        }
        thr[qq] = th;
    }

    // ---- pass C: membership re-scan; collect (d^2, idx) of hits ----
    #pragma unroll 2
    for (int t = 0; t < SCAN; ++t) {
        const int s = t * G + l;
        const float4 m = s_m[s];
        #pragma unroll
        for (int qq = 0; qq < QL; ++qq) {
            const float x = KEYX(m, qq);
            if (x <= thr[qq]) {
                const float dc = fmaxf(__fadd_rn(x, q2[qq]), 0.0f);  // d^2
                const u64 key = ((u64)__float_as_uint(dc) << 32) | (unsigned)s;
                const int qid = g * QL + qq;
                const int pos = atomicAdd(&s_cnt[qid], 1);
                if (pos < CAP) s_items[qid * CAP + pos] = key;
            }
        }
    }
    __syncthreads();

    // ---- rare tie fix (lanes 0..QL-1 of each group, one query each) ----
    if (l < QL) {
        const int qid = g * QL + l;
        int cnt = s_cnt[qid];
        if (cnt > KNN) {
            cnt = cnt < CAP ? cnt : CAP;
            u64 best[KNN];
            #pragma unroll
            for (int j = 0; j < KNN; ++j) best[j] = ~0ull;
            for (int i = 0; i < cnt; ++i) {
                const u64 key = s_items[qid * CAP + i];
                bool f[KNN];
                #pragma unroll
                for (int j = 0; j < KNN; ++j) f[j] = key < best[j];
                #pragma unroll
                for (int j = KNN - 1; j >= 1; --j)
                    best[j] = f[j-1] ? best[j-1] : (f[j] ? key : best[j]);
                best[0] = f[0] ? key : best[0];
            }
            #pragma unroll
            for (int j = 0; j < KNN; ++j) s_items[qid * CAP + j] = best[j];
        }
    }
    __syncthreads();

    // ---- weights: 16 lanes = 2 queries x 8 slots ----
    {
        const int qq  = l >> 3;                // 0..1
        const int k   = l & 7;
        const int qid = g * QL + qq;
        const u64 key = s_items[qid * CAP + k];
        const float d2v = __uint_as_float((unsigned)(key >> 32));
        const int   idx = (int)(unsigned)(key & 0xFFFFFFFFu);
        const float w   = 1.0f / (sqrtf(d2v) + 1e-8f);
        float ws = w;
        ws += __shfl_xor(ws, 1, 64);
        ws += __shfl_xor(ws, 2, 64);
        ws += __shfl_xor(ws, 4, 64);
        s_idx[qid * KNN + k] = idx;
        s_w  [qid * KNN + k] = w / ws;
    }
    __syncthreads();

    // ---- phase B: one wave per query, 64 lanes x float4 = 256 features ----
    const int wave = tid >> 6;       // 0..7
    const int lane = tid & 63;
    const float* fb = sf + (size_t)b * NS * FDIM;
    #pragma unroll 1
    for (int j = 0; j < QPB / 8; ++j) {          // 8 queries per wave
        const int ql = wave * (QPB / 8) + j;
        float4 acc = {0.f, 0.f, 0.f, 0.f};
        #pragma unroll
        for (int kk = 0; kk < KNN; ++kk) {
            const int   sid = s_idx[ql * KNN + kk];   // LDS broadcast
            const float wk  = s_w  [ql * KNN + kk];
            const float4 v = ((const float4*)(fb + (size_t)sid * FDIM))[lane];
            acc.x += wk * v.x; acc.y += wk * v.y;
            acc.z += wk * v.z; acc.w += wk * v.w;
        }
        ((float4*)(out + (size_t)(q0 + ql) * FDIM))[lane] = acc;
    }
}

extern "C" void kernel_launch(void* const* d_in, const int* in_sizes, int n_in,
                              void* d_out, int out_size, void* d_ws, size_t ws_size,
                              hipStream_t stream) {
    const float* qc = (const float*)d_in[0];   // query_coords  (4,8192,3)
    const float* sc = (const float*)d_in[1];   // sensor_coords (4096,3)
    const float* sf = (const float*)d_in[2];   // sensor_features (4,4096,256)
    float* out = (float*)d_out;                // (4,8192,256)

    dim3 grid((BB * NQ) / QPB);                // 512 blocks
    dim3 block(NT);
    idw_kernel<<<grid, block, 0, stream>>>(qc, sc, sf, out);
}